// Round 1
// baseline (434.169 us; speedup 1.0000x reference)
//
#include <hip/hip_runtime.h>

typedef unsigned short u16;
typedef __attribute__((ext_vector_type(8))) short bf16x8;   // 8 bf16 in 4 VGPRs
typedef __attribute__((ext_vector_type(4))) float f32x4;

#define GLDS16(gptr, lptr)                                                        \
  __builtin_amdgcn_global_load_lds(                                               \
      (__attribute__((address_space(1))) const void*)(gptr),                      \
      (__attribute__((address_space(3))) void*)(lptr), 16, 0, 0)

__device__ __forceinline__ u16 f2bf(float f) {
  union { float f; unsigned u; } v; v.f = f;
  unsigned r = v.u + 0x7fffu + ((v.u >> 16) & 1u);   // RNE, finite inputs only
  return (u16)(r >> 16);
}

// ---------------- prep: fp32 -> bf16 cast ----------------
__global__ void k_f32_to_bf16(const float* __restrict__ in, u16* __restrict__ out, int n4) {
  int i = blockIdx.x * 256 + threadIdx.x;
  if (i < n4) {
    float4 f = reinterpret_cast<const float4*>(in)[i];
    ushort4 u;
    u.x = f2bf(f.x); u.y = f2bf(f.y); u.z = f2bf(f.z); u.w = f2bf(f.w);
    reinterpret_cast<ushort4*>(out)[i] = u;
  }
}

// ---------------- prep: effective weight W_eff + b_eff ----------------
// o in [0,1024): q slice  -> W_qkv + W_lora + (B_q A_q)/8, bias b_lora
// o in [1024,2048): k     -> W_qkv only, bias 0
// o in [2048,3072): v     -> W_qkv + W_lora + (B_v A_v)/8, bias b_lora
__global__ void k_prep_weff(const float* __restrict__ Wqkv, const float* __restrict__ Wlora,
                            const float* __restrict__ blora,
                            const float* __restrict__ Aq, const float* __restrict__ Bq,
                            const float* __restrict__ Av, const float* __restrict__ Bv,
                            u16* __restrict__ Weff, float* __restrict__ beff) {
  int idx = blockIdx.x * 256 + threadIdx.x;  // < 3072*1024
  int o = idx >> 10, c = idx & 1023;
  float w = Wqkv[idx];
  if (o < 1024) {
    float lr = 0.f;
#pragma unroll
    for (int r = 0; r < 8; ++r) lr += Bq[o * 8 + r] * Aq[r * 1024 + c];
    w += Wlora[idx] + 0.125f * lr;
  } else if (o >= 2048) {
    int o2 = o - 2048;
    float lr = 0.f;
#pragma unroll
    for (int r = 0; r < 8; ++r) lr += Bv[o2 * 8 + r] * Av[r * 1024 + c];
    w += Wlora[idx] + 0.125f * lr;
  }
  Weff[idx] = f2bf(w);
  if (c == 0) beff[o] = (o < 1024 || o >= 2048) ? blora[o] : 0.f;
}

// ---------------- GEMM1: Y[8192][3072] = Xb @ Weff^T + beff ----------------
// Also: q slice scaled by 0.125 (exact), v slice additionally scattered
// transposed into Vt[(b*1024 + hd)][2048] for the attention PV B-operand.
__global__ __launch_bounds__(256, 2)
void k_gemm_qkv(const u16* __restrict__ Xb, const u16* __restrict__ Weff,
                const float* __restrict__ beff, u16* __restrict__ Y, u16* __restrict__ Vt) {
  __shared__ u16 As[128 * 32], Bs[128 * 32];
  const int tid = threadIdx.x, lane = tid & 63, wave = tid >> 6;
  const int lr = lane & 15, lg = lane >> 4;
  const int wr = wave >> 1, wc = wave & 1;
  const int m0 = blockIdx.y * 128, n0 = blockIdx.x * 128;
  f32x4 acc[4][4] = {};

  for (int k0 = 0; k0 < 1024; k0 += 32) {
    // stage (XOR-swizzled on the GLOBAL side; LDS dest stays linear)
#pragma unroll
    for (int i = 0; i < 2; ++i) {
      int gc = ((tid & 3) ^ ((tid >> 2) & 3)) << 3;
      GLDS16(Xb + (size_t)(m0 + i * 64 + (tid >> 2)) * 1024 + k0 + gc, As + i * 2048 + wave * 512);
      GLDS16(Weff + (size_t)(n0 + i * 64 + (tid >> 2)) * 1024 + k0 + gc, Bs + i * 2048 + wave * 512);
    }
    __syncthreads();
    bf16x8 af[4], bfr[4];
#pragma unroll
    for (int t = 0; t < 4; ++t) {
      int ch = ((lg ^ (lr & 3)) & 3) << 3;
      af[t]  = *reinterpret_cast<const bf16x8*>(As + (wr * 64 + t * 16 + lr) * 32 + ch);
      bfr[t] = *reinterpret_cast<const bf16x8*>(Bs + (wc * 64 + t * 16 + lr) * 32 + ch);
    }
#pragma unroll
    for (int mi = 0; mi < 4; ++mi)
#pragma unroll
      for (int ni = 0; ni < 4; ++ni)
        acc[mi][ni] = __builtin_amdgcn_mfma_f32_16x16x32_bf16(af[mi], bfr[ni], acc[mi][ni], 0, 0, 0);
    __syncthreads();
  }

#pragma unroll
  for (int mi = 0; mi < 4; ++mi) {
    int row = m0 + wr * 64 + mi * 16 + (lg << 2);
#pragma unroll
    for (int ni = 0; ni < 4; ++ni) {
      int col = n0 + wc * 64 + ni * 16 + lr;
      float bias = beff[col];
      float vs[4];
#pragma unroll
      for (int j = 0; j < 4; ++j) {
        float v = acc[mi][ni][j] + bias;
        if (col < 1024) v *= 0.125f;  // fold softmax scale into Q (exact pow2)
        vs[j] = v;
        Y[(size_t)(row + j) * 3072 + col] = f2bf(v);
      }
      if (col >= 2048) {
        int hd = col - 2048;
        int bb = row >> 11, n = row & 2047;
        ushort4 pk;
        pk.x = f2bf(vs[0]); pk.y = f2bf(vs[1]); pk.z = f2bf(vs[2]); pk.w = f2bf(vs[3]);
        *reinterpret_cast<ushort4*>(Vt + (size_t)(bb * 1024 + hd) * 2048 + n) = pk;
      }
    }
  }
}

// ---------------- flash attention ----------------
// Block: one (b,h), 128 Q rows; 4 waves x 32 rows each.  64-key tiles.
__global__ __launch_bounds__(256, 2)
void k_attn(const u16* __restrict__ Y, const u16* __restrict__ Vt, u16* __restrict__ Oa) {
  __shared__ u16 Ks[64 * 64], Vs[64 * 64], Ps[4 * 32 * 64];
  const int tid = threadIdx.x, lane = tid & 63, wave = tid >> 6;
  const int b = blockIdx.y >> 4, h = blockIdx.y & 15;
  const int q0 = blockIdx.x * 128;
  const int lr = lane & 15, lg = lane >> 4;

  bf16x8 qa[2][2];
#pragma unroll
  for (int g = 0; g < 2; ++g) {
    size_t row = (size_t)(b * 2048 + q0 + wave * 32 + g * 16 + lr);
#pragma unroll
    for (int hf = 0; hf < 2; ++hf)
      qa[g][hf] = *reinterpret_cast<const bf16x8*>(Y + row * 3072 + h * 64 + hf * 32 + lg * 8);
  }

  float m_run[2][4], l_run[2][4];
  f32x4 oacc[2][4] = {};
#pragma unroll
  for (int g = 0; g < 2; ++g)
#pragma unroll
    for (int j = 0; j < 4; ++j) { m_run[g][j] = -1e30f; l_run[g][j] = 0.f; }

  const int sr = tid >> 3, sc = tid & 7;
  for (int kt = 0; kt < 32; ++kt) {
    const int key0 = kt * 64;
#pragma unroll
    for (int i = 0; i < 2; ++i) {
      int r = i * 32 + sr;
      int gc = (sc ^ (r & 7)) << 3;
      GLDS16(Y + (size_t)(b * 2048 + key0 + r) * 3072 + 1024 + h * 64 + gc, Ks + i * 2048 + wave * 512);
      GLDS16(Vt + (size_t)(b * 1024 + h * 64 + r) * 2048 + key0 + gc,       Vs + i * 2048 + wave * 512);
    }
    __syncthreads();

    bf16x8 kb[4][2], vb[4][2];
#pragma unroll
    for (int s = 0; s < 4; ++s) {
      int row = s * 16 + lr;
#pragma unroll
      for (int hf = 0; hf < 2; ++hf) {
        int ch = ((hf * 4 + lg) ^ (row & 7)) << 3;
        kb[s][hf] = *reinterpret_cast<const bf16x8*>(Ks + row * 64 + ch);
        vb[s][hf] = *reinterpret_cast<const bf16x8*>(Vs + row * 64 + ch);
      }
    }

#pragma unroll
    for (int g = 0; g < 2; ++g) {
      f32x4 s4[4] = {};
#pragma unroll
      for (int s = 0; s < 4; ++s)
#pragma unroll
        for (int hf = 0; hf < 2; ++hf)
          s4[s] = __builtin_amdgcn_mfma_f32_16x16x32_bf16(qa[g][hf], kb[s][hf], s4[s], 0, 0, 0);

      float mnew[4], alpha[4];
#pragma unroll
      for (int j = 0; j < 4; ++j) {
        float t = fmaxf(fmaxf(s4[0][j], s4[1][j]), fmaxf(s4[2][j], s4[3][j]));
        t = fmaxf(t, __shfl_xor(t, 1));
        t = fmaxf(t, __shfl_xor(t, 2));
        t = fmaxf(t, __shfl_xor(t, 4));
        t = fmaxf(t, __shfl_xor(t, 8));
        float mn = fmaxf(m_run[g][j], t);
        alpha[j] = __expf(m_run[g][j] - mn);
        m_run[g][j] = mn;
        mnew[j] = mn;
      }
      float rs[4] = {0.f, 0.f, 0.f, 0.f};
#pragma unroll
      for (int s = 0; s < 4; ++s) {
        int colc = s * 2 + (lr >> 3);
#pragma unroll
        for (int j = 0; j < 4; ++j) {
          float p = __expf(s4[s][j] - mnew[j]);
          rs[j] += p;
          int row = g * 16 + (lg << 2) + j;
          Ps[wave * 2048 + row * 64 + ((colc ^ (row & 7)) << 3) + (lane & 7)] = f2bf(p);
        }
      }
#pragma unroll
      for (int j = 0; j < 4; ++j) {
        float t = rs[j];
        t += __shfl_xor(t, 1); t += __shfl_xor(t, 2);
        t += __shfl_xor(t, 4); t += __shfl_xor(t, 8);
        l_run[g][j] = l_run[g][j] * alpha[j] + t;
      }
#pragma unroll
      for (int dt = 0; dt < 4; ++dt)
#pragma unroll
        for (int j = 0; j < 4; ++j) oacc[g][dt][j] *= alpha[j];

      // wave-local LDS visibility for the P round-trip (rule 18: fence the scheduler)
      asm volatile("s_waitcnt lgkmcnt(0)" ::: "memory");
      __builtin_amdgcn_sched_barrier(0);

#pragma unroll
      for (int hf = 0; hf < 2; ++hf) {
        int prow = g * 16 + lr;
        int ch = ((hf * 4 + lg) ^ (prow & 7)) << 3;
        bf16x8 pa = *reinterpret_cast<const bf16x8*>(Ps + wave * 2048 + prow * 64 + ch);
#pragma unroll
        for (int dt = 0; dt < 4; ++dt)
          oacc[g][dt] = __builtin_amdgcn_mfma_f32_16x16x32_bf16(pa, vb[dt][hf], oacc[g][dt], 0, 0, 0);
      }
    }
    __syncthreads();
  }

#pragma unroll
  for (int g = 0; g < 2; ++g) {
    int rowb = b * 2048 + q0 + wave * 32 + g * 16 + (lg << 2);
#pragma unroll
    for (int dt = 0; dt < 4; ++dt) {
      int col = h * 64 + dt * 16 + lr;
#pragma unroll
      for (int j = 0; j < 4; ++j) {
        float v = oacc[g][dt][j] / l_run[g][j];
        Oa[(size_t)(rowb + j) * 1024 + col] = f2bf(v);
      }
    }
  }
}

// ---------------- GEMM2: out[8192][1024] = Oa @ Wout^T + b_out (fp32) ----------------
__global__ __launch_bounds__(256, 2)
void k_gemm_out(const u16* __restrict__ Ob, const u16* __restrict__ Wb,
                const float* __restrict__ bout, float* __restrict__ out) {
  __shared__ u16 As[128 * 32], Bs[128 * 32];
  const int tid = threadIdx.x, lane = tid & 63, wave = tid >> 6;
  const int lr = lane & 15, lg = lane >> 4;
  const int wr = wave >> 1, wc = wave & 1;
  const int m0 = blockIdx.y * 128, n0 = blockIdx.x * 128;
  f32x4 acc[4][4] = {};

  for (int k0 = 0; k0 < 1024; k0 += 32) {
#pragma unroll
    for (int i = 0; i < 2; ++i) {
      int gc = ((tid & 3) ^ ((tid >> 2) & 3)) << 3;
      GLDS16(Ob + (size_t)(m0 + i * 64 + (tid >> 2)) * 1024 + k0 + gc, As + i * 2048 + wave * 512);
      GLDS16(Wb + (size_t)(n0 + i * 64 + (tid >> 2)) * 1024 + k0 + gc, Bs + i * 2048 + wave * 512);
    }
    __syncthreads();
    bf16x8 af[4], bfr[4];
#pragma unroll
    for (int t = 0; t < 4; ++t) {
      int ch = ((lg ^ (lr & 3)) & 3) << 3;
      af[t]  = *reinterpret_cast<const bf16x8*>(As + (wr * 64 + t * 16 + lr) * 32 + ch);
      bfr[t] = *reinterpret_cast<const bf16x8*>(Bs + (wc * 64 + t * 16 + lr) * 32 + ch);
    }
#pragma unroll
    for (int mi = 0; mi < 4; ++mi)
#pragma unroll
      for (int ni = 0; ni < 4; ++ni)
        acc[mi][ni] = __builtin_amdgcn_mfma_f32_16x16x32_bf16(af[mi], bfr[ni], acc[mi][ni], 0, 0, 0);
    __syncthreads();
  }

#pragma unroll
  for (int mi = 0; mi < 4; ++mi) {
    int row = m0 + wr * 64 + mi * 16 + (lg << 2);
#pragma unroll
    for (int ni = 0; ni < 4; ++ni) {
      int col = n0 + wc * 64 + ni * 16 + lr;
      float bias = bout[col];
#pragma unroll
      for (int j = 0; j < 4; ++j)
        out[(size_t)(row + j) * 1024 + col] = acc[mi][ni][j] + bias;
    }
  }
}

extern "C" void kernel_launch(void* const* d_in, const int* in_sizes, int n_in,
                              void* d_out, int out_size, void* d_ws, size_t ws_size,
                              hipStream_t stream) {
  const float* x     = (const float*)d_in[0];
  const float* Wqkv  = (const float*)d_in[1];
  const float* Wlora = (const float*)d_in[2];
  const float* blora = (const float*)d_in[3];
  const float* Aq    = (const float*)d_in[4];
  const float* Bq    = (const float*)d_in[5];
  const float* Av    = (const float*)d_in[6];
  const float* Bv    = (const float*)d_in[7];
  const float* Wout  = (const float*)d_in[8];
  const float* bout  = (const float*)d_in[9];
  float* out = (float*)d_out;

  char* w = (char*)d_ws;
  auto alloc = [&](size_t bytes) { char* p = w; w += (bytes + 255) & ~(size_t)255; return p; };
  u16*   Xb    = (u16*)alloc((size_t)8192 * 1024 * 2);   // x bf16  (reused as Oa later)
  u16*   Weff  = (u16*)alloc((size_t)3072 * 1024 * 2);
  float* beff  = (float*)alloc((size_t)3072 * 4);
  u16*   Woutb = (u16*)alloc((size_t)1024 * 1024 * 2);
  u16*   Y     = (u16*)alloc((size_t)8192 * 3072 * 2);   // qkv (q pre-scaled by 1/8)
  u16*   Vt    = (u16*)alloc((size_t)4096 * 1024 * 2 * 2); // [(b*16+h)*64+d][2048] bf16
  u16*   Oa    = Xb;  // alias: Xb is dead after GEMM1

  k_f32_to_bf16<<<dim3(8192), dim3(256), 0, stream>>>(x, Xb, 8192 * 1024 / 4);
  k_f32_to_bf16<<<dim3(1024), dim3(256), 0, stream>>>(Wout, Woutb, 1024 * 1024 / 4);
  k_prep_weff<<<dim3(12288), dim3(256), 0, stream>>>(Wqkv, Wlora, blora, Aq, Bq, Av, Bv, Weff, beff);
  k_gemm_qkv<<<dim3(24, 64), dim3(256), 0, stream>>>(Xb, Weff, beff, Y, Vt);
  k_attn<<<dim3(16, 64), dim3(256), 0, stream>>>(Y, Vt, Oa);
  k_gemm_out<<<dim3(8, 64), dim3(256), 0, stream>>>(Oa, Woutb, bout, out);
}

// Round 3
// 354.440 us; speedup vs baseline: 1.2249x; 1.2249x over previous
//
#include <hip/hip_runtime.h>
#include <hip/hip_bf16.h>

typedef unsigned short u16;
typedef unsigned int u32;
typedef __attribute__((ext_vector_type(8))) short bf16x8;   // 8 bf16 in 4 VGPRs
typedef __attribute__((ext_vector_type(4))) float f32x4;

#define GLDS16(gptr, lptr)                                                        \
  __builtin_amdgcn_global_load_lds(                                               \
      (__attribute__((address_space(1))) const void*)(gptr),                      \
      (__attribute__((address_space(3))) void*)(lptr), 16, 0, 0)

__device__ __forceinline__ u16 f2bf(float f) {
  union { float f; unsigned u; } v; v.f = f;
  unsigned r = v.u + 0x7fffu + ((v.u >> 16) & 1u);   // RNE, finite inputs only
  return (u16)(r >> 16);
}

// pack two f32 -> one u32 of 2 bf16 (RNE) — compiler emits v_cvt_pk_bf16_f32
__device__ __forceinline__ u32 pack_bf2(float a, float b) {
  union { __hip_bfloat162 h2; u32 u; } v;
  v.h2 = __float22bfloat162_rn(make_float2(a, b));
  return v.u;
}

// ---------------- prep: fp32 -> bf16 cast ----------------
__global__ void k_f32_to_bf16(const float* __restrict__ in, u16* __restrict__ out, int n4) {
  int i = blockIdx.x * 256 + threadIdx.x;
  if (i < n4) {
    float4 f = reinterpret_cast<const float4*>(in)[i];
    ushort4 u;
    u.x = f2bf(f.x); u.y = f2bf(f.y); u.z = f2bf(f.z); u.w = f2bf(f.w);
    reinterpret_cast<ushort4*>(out)[i] = u;
  }
}

// ---------------- prep: effective weight W_eff + b_eff ----------------
__global__ void k_prep_weff(const float* __restrict__ Wqkv, const float* __restrict__ Wlora,
                            const float* __restrict__ blora,
                            const float* __restrict__ Aq, const float* __restrict__ Bq,
                            const float* __restrict__ Av, const float* __restrict__ Bv,
                            u16* __restrict__ Weff, float* __restrict__ beff) {
  int idx = blockIdx.x * 256 + threadIdx.x;  // < 3072*1024
  int o = idx >> 10, c = idx & 1023;
  float w = Wqkv[idx];
  if (o < 1024) {
    float lr = 0.f;
#pragma unroll
    for (int r = 0; r < 8; ++r) lr += Bq[o * 8 + r] * Aq[r * 1024 + c];
    w += Wlora[idx] + 0.125f * lr;
  } else if (o >= 2048) {
    int o2 = o - 2048;
    float lr = 0.f;
#pragma unroll
    for (int r = 0; r < 8; ++r) lr += Bv[o2 * 8 + r] * Av[r * 1024 + c];
    w += Wlora[idx] + 0.125f * lr;
  }
  Weff[idx] = f2bf(w);
  if (c == 0) beff[o] = (o < 1024 || o >= 2048) ? blora[o] : 0.f;
}

// ---------------- GEMM1: Y[8192][3072] = Xb @ Weff^T + beff ----------------
__global__ __launch_bounds__(256, 2)
void k_gemm_qkv(const u16* __restrict__ Xb, const u16* __restrict__ Weff,
                const float* __restrict__ beff, u16* __restrict__ Y, u16* __restrict__ Vt) {
  __shared__ u16 As[128 * 32], Bs[128 * 32];
  const int tid = threadIdx.x, lane = tid & 63, wave = tid >> 6;
  const int lr = lane & 15, lg = lane >> 4;
  const int wr = wave >> 1, wc = wave & 1;
  const int m0 = blockIdx.y * 128, n0 = blockIdx.x * 128;
  f32x4 acc[4][4] = {};

  for (int k0 = 0; k0 < 1024; k0 += 32) {
#pragma unroll
    for (int i = 0; i < 2; ++i) {
      int gc = ((tid & 3) ^ ((tid >> 2) & 3)) << 3;
      GLDS16(Xb + (size_t)(m0 + i * 64 + (tid >> 2)) * 1024 + k0 + gc, As + i * 2048 + wave * 512);
      GLDS16(Weff + (size_t)(n0 + i * 64 + (tid >> 2)) * 1024 + k0 + gc, Bs + i * 2048 + wave * 512);
    }
    __syncthreads();
    bf16x8 af[4], bfr[4];
#pragma unroll
    for (int t = 0; t < 4; ++t) {
      int ch = ((lg ^ (lr & 3)) & 3) << 3;
      af[t]  = *reinterpret_cast<const bf16x8*>(As + (wr * 64 + t * 16 + lr) * 32 + ch);
      bfr[t] = *reinterpret_cast<const bf16x8*>(Bs + (wc * 64 + t * 16 + lr) * 32 + ch);
    }
#pragma unroll
    for (int mi = 0; mi < 4; ++mi)
#pragma unroll
      for (int ni = 0; ni < 4; ++ni)
        acc[mi][ni] = __builtin_amdgcn_mfma_f32_16x16x32_bf16(af[mi], bfr[ni], acc[mi][ni], 0, 0, 0);
    __syncthreads();
  }

#pragma unroll
  for (int mi = 0; mi < 4; ++mi) {
    int row = m0 + wr * 64 + mi * 16 + (lg << 2);
#pragma unroll
    for (int ni = 0; ni < 4; ++ni) {
      int col = n0 + wc * 64 + ni * 16 + lr;
      float bias = beff[col];
      float vs[4];
#pragma unroll
      for (int j = 0; j < 4; ++j) {
        float v = acc[mi][ni][j] + bias;
        if (col < 1024) v *= 0.125f;  // fold softmax scale into Q (exact pow2)
        vs[j] = v;
        Y[(size_t)(row + j) * 3072 + col] = f2bf(v);
      }
      if (col >= 2048) {
        int hd = col - 2048;
        int bb = row >> 11, n = row & 2047;
        ushort4 pk;
        pk.x = f2bf(vs[0]); pk.y = f2bf(vs[1]); pk.z = f2bf(vs[2]); pk.w = f2bf(vs[3]);
        *reinterpret_cast<ushort4*>(Vt + (size_t)(bb * 1024 + hd) * 2048 + n) = pk;
      }
    }
  }
}

// ---------------- flash attention (swapped-QK^T, in-register softmax) ----------------
// Block: one (b,h), 128 Q rows; 4 waves x 32 rows each.  64-key tiles.
// S^T = mfma(K,Q): lane holds 16 scores of q-row (lane&15); m/l are per-lane scalars.
__global__ __launch_bounds__(256, 3)
void k_attn(const u16* __restrict__ Y, const u16* __restrict__ Vt, u16* __restrict__ Oa) {
  __shared__ u16 Ks[64 * 64], Vs[64 * 64];
  __shared__ u32 Pp[4 * 16 * 32];   // per wave: 16 qrows x 32 u32 (64 keys bf16), XOR-swizzled
  const int tid = threadIdx.x, lane = tid & 63, wave = tid >> 6;
  const int b = blockIdx.y >> 4, h = blockIdx.y & 15;
  const int q0 = blockIdx.x * 128;
  const int lr = lane & 15, lg = lane >> 4;

  // Q fragments (B-operand: n=qrow=lr, k-chunk = hf*32 + lg*8) — Q pre-scaled by 1/8
  bf16x8 qa[2][2];
#pragma unroll
  for (int g = 0; g < 2; ++g) {
    size_t row = (size_t)(b * 2048 + q0 + wave * 32 + g * 16 + lr);
#pragma unroll
    for (int hf = 0; hf < 2; ++hf)
      qa[g][hf] = *reinterpret_cast<const bf16x8*>(Y + row * 3072 + h * 64 + hf * 32 + lg * 8);
  }

  float m_run[2] = {-1e30f, -1e30f}, l_run[2] = {0.f, 0.f};
  f32x4 oacc[2][4] = {};

  const int sr = tid >> 3, sc = tid & 7;
  const u32 pbase = wave * 512 + lr * 32;          // u32 index of this lane's P row
  const u32 pswz  = (lr & 7) << 4;                 // byte-XOR swizzle field

  for (int kt = 0; kt < 32; ++kt) {
    const int key0 = kt * 64;
#pragma unroll
    for (int i = 0; i < 2; ++i) {
      int r = i * 32 + sr;
      int gc = (sc ^ (r & 7)) << 3;
      GLDS16(Y + (size_t)(b * 2048 + key0 + r) * 3072 + 1024 + h * 64 + gc, Ks + i * 2048 + wave * 512);
      GLDS16(Vt + (size_t)(b * 1024 + h * 64 + r) * 2048 + key0 + gc,       Vs + i * 2048 + wave * 512);
    }
    __syncthreads();

    bf16x8 kb[4][2], vb[4][2];
#pragma unroll
    for (int s = 0; s < 4; ++s) {
      int row = s * 16 + lr;
#pragma unroll
      for (int hf = 0; hf < 2; ++hf) {
        int ch = ((hf * 4 + lg) ^ (row & 7)) << 3;
        kb[s][hf] = *reinterpret_cast<const bf16x8*>(Ks + row * 64 + ch);
        vb[s][hf] = *reinterpret_cast<const bf16x8*>(Vs + row * 64 + ch);
      }
    }

#pragma unroll
    for (int g = 0; g < 2; ++g) {
      // S^T tiles: C row = key (lg*4+j within s-tile), C col = qrow (lr)
      f32x4 p4[4] = {};
      __builtin_amdgcn_s_setprio(1);
#pragma unroll
      for (int s = 0; s < 4; ++s)
#pragma unroll
        for (int hf = 0; hf < 2; ++hf)
          p4[s] = __builtin_amdgcn_mfma_f32_16x16x32_bf16(kb[s][hf], qa[g][hf], p4[s], 0, 0, 0);
      __builtin_amdgcn_s_setprio(0);

      // row max: in-lane 16 values, then across the 4 lg-groups
      float tmax = fmaxf(fmaxf(p4[0][0], p4[0][1]), fmaxf(p4[0][2], p4[0][3]));
#pragma unroll
      for (int s = 1; s < 4; ++s)
        tmax = fmaxf(tmax, fmaxf(fmaxf(p4[s][0], p4[s][1]), fmaxf(p4[s][2], p4[s][3])));
      tmax = fmaxf(tmax, __shfl_xor(tmax, 16));
      tmax = fmaxf(tmax, __shfl_xor(tmax, 32));

      // defer-max (T13, THR=8): only rescale when the running max really grew
      if (__any(tmax > m_run[g] + 8.f)) {
        float mnew = fmaxf(m_run[g], tmax);
        float alpha = __expf(m_run[g] - mnew);
        m_run[g] = mnew;
        l_run[g] *= alpha;
        float abc[4];
#pragma unroll
        for (int j = 0; j < 4; ++j) abc[j] = __shfl(alpha, (lg << 2) + j);
#pragma unroll
        for (int dt = 0; dt < 4; ++dt)
#pragma unroll
          for (int j = 0; j < 4; ++j) oacc[g][dt][j] *= abc[j];
      }

      // P = exp(S - m), pack to bf16 pairs, row-sum
      float rs = 0.f;
      u32 w[4][2];
#pragma unroll
      for (int s = 0; s < 4; ++s) {
        float e0 = __expf(p4[s][0] - m_run[g]);
        float e1 = __expf(p4[s][1] - m_run[g]);
        float e2 = __expf(p4[s][2] - m_run[g]);
        float e3 = __expf(p4[s][3] - m_run[g]);
        rs += (e0 + e1) + (e2 + e3);
        w[s][0] = pack_bf2(e0, e1);
        w[s][1] = pack_bf2(e2, e3);
      }
      rs += __shfl_xor(rs, 16);
      rs += __shfl_xor(rs, 32);
      l_run[g] += rs;

      // scatter P^T into per-wave LDS: key K lives at u32 index K/2 of row lr
      // this lane's keys: s*16 + lg*4 + j  ->  byte offset s*32 + lg*8 (+4 per pair)
#pragma unroll
      for (int s = 0; s < 4; ++s) {
        u32 ui = pbase + ((((u32)(s * 32 + lg * 8)) ^ pswz) >> 2);
        *reinterpret_cast<uint2*>(&Pp[ui]) = make_uint2(w[s][0], w[s][1]);
      }
      asm volatile("s_waitcnt lgkmcnt(0)" ::: "memory");
      __builtin_amdgcn_sched_barrier(0);

      // PV: A-frag chunk kk = keys kk*32 + lg*8 .. +7  (matches vb's k-slot convention)
      __builtin_amdgcn_s_setprio(1);
#pragma unroll
      for (int kk = 0; kk < 2; ++kk) {
        u32 ur = pbase + ((((u32)(kk * 64 + lg * 16)) ^ pswz) >> 2);
        bf16x8 pa = *reinterpret_cast<const bf16x8*>(&Pp[ur]);
#pragma unroll
        for (int dt = 0; dt < 4; ++dt)
          oacc[g][dt] = __builtin_amdgcn_mfma_f32_16x16x32_bf16(pa, vb[dt][kk], oacc[g][dt], 0, 0, 0);
      }
      __builtin_amdgcn_s_setprio(0);
    }
    __syncthreads();
  }

#pragma unroll
  for (int g = 0; g < 2; ++g) {
    float lbc[4];
#pragma unroll
    for (int j = 0; j < 4; ++j)
      lbc[j] = __builtin_amdgcn_rcpf(__shfl(l_run[g], (lg << 2) + j));
    int rowb = b * 2048 + q0 + wave * 32 + g * 16 + (lg << 2);
#pragma unroll
    for (int dt = 0; dt < 4; ++dt) {
      int col = h * 64 + dt * 16 + lr;
#pragma unroll
      for (int j = 0; j < 4; ++j) {
        float v = oacc[g][dt][j] * lbc[j];
        Oa[(size_t)(rowb + j) * 1024 + col] = f2bf(v);
      }
    }
  }
}

// ---------------- GEMM2: out[8192][1024] = Oa @ Wout^T + b_out (fp32) ----------------
__global__ __launch_bounds__(256, 2)
void k_gemm_out(const u16* __restrict__ Ob, const u16* __restrict__ Wb,
                const float* __restrict__ bout, float* __restrict__ out) {
  __shared__ u16 As[128 * 32], Bs[128 * 32];
  const int tid = threadIdx.x, lane = tid & 63, wave = tid >> 6;
  const int lr = lane & 15, lg = lane >> 4;
  const int wr = wave >> 1, wc = wave & 1;
  const int m0 = blockIdx.y * 128, n0 = blockIdx.x * 128;
  f32x4 acc[4][4] = {};

  for (int k0 = 0; k0 < 1024; k0 += 32) {
#pragma unroll
    for (int i = 0; i < 2; ++i) {
      int gc = ((tid & 3) ^ ((tid >> 2) & 3)) << 3;
      GLDS16(Ob + (size_t)(m0 + i * 64 + (tid >> 2)) * 1024 + k0 + gc, As + i * 2048 + wave * 512);
      GLDS16(Wb + (size_t)(n0 + i * 64 + (tid >> 2)) * 1024 + k0 + gc, Bs + i * 2048 + wave * 512);
    }
    __syncthreads();
    bf16x8 af[4], bfr[4];
#pragma unroll
    for (int t = 0; t < 4; ++t) {
      int ch = ((lg ^ (lr & 3)) & 3) << 3;
      af[t]  = *reinterpret_cast<const bf16x8*>(As + (wr * 64 + t * 16 + lr) * 32 + ch);
      bfr[t] = *reinterpret_cast<const bf16x8*>(Bs + (wc * 64 + t * 16 + lr) * 32 + ch);
    }
#pragma unroll
    for (int mi = 0; mi < 4; ++mi)
#pragma unroll
      for (int ni = 0; ni < 4; ++ni)
        acc[mi][ni] = __builtin_amdgcn_mfma_f32_16x16x32_bf16(af[mi], bfr[ni], acc[mi][ni], 0, 0, 0);
    __syncthreads();
  }

#pragma unroll
  for (int mi = 0; mi < 4; ++mi) {
    int row = m0 + wr * 64 + mi * 16 + (lg << 2);
#pragma unroll
    for (int ni = 0; ni < 4; ++ni) {
      int col = n0 + wc * 64 + ni * 16 + lr;
      float bias = bout[col];
#pragma unroll
      for (int j = 0; j < 4; ++j)
        out[(size_t)(row + j) * 1024 + col] = acc[mi][ni][j] + bias;
    }
  }
}

extern "C" void kernel_launch(void* const* d_in, const int* in_sizes, int n_in,
                              void* d_out, int out_size, void* d_ws, size_t ws_size,
                              hipStream_t stream) {
  const float* x     = (const float*)d_in[0];
  const float* Wqkv  = (const float*)d_in[1];
  const float* Wlora = (const float*)d_in[2];
  const float* blora = (const float*)d_in[3];
  const float* Aq    = (const float*)d_in[4];
  const float* Bq    = (const float*)d_in[5];
  const float* Av    = (const float*)d_in[6];
  const float* Bv    = (const float*)d_in[7];
  const float* Wout  = (const float*)d_in[8];
  const float* bout  = (const float*)d_in[9];
  float* out = (float*)d_out;

  char* w = (char*)d_ws;
  auto alloc = [&](size_t bytes) { char* p = w; w += (bytes + 255) & ~(size_t)255; return p; };
  u16*   Xb    = (u16*)alloc((size_t)8192 * 1024 * 2);   // x bf16  (reused as Oa later)
  u16*   Weff  = (u16*)alloc((size_t)3072 * 1024 * 2);
  float* beff  = (float*)alloc((size_t)3072 * 4);
  u16*   Woutb = (u16*)alloc((size_t)1024 * 1024 * 2);
  u16*   Y     = (u16*)alloc((size_t)8192 * 3072 * 2);   // qkv (q pre-scaled by 1/8)
  u16*   Vt    = (u16*)alloc((size_t)4096 * 1024 * 2 * 2); // [(b*16+h)*64+d][2048] bf16
  u16*   Oa    = Xb;  // alias: Xb is dead after GEMM1

  k_f32_to_bf16<<<dim3(8192), dim3(256), 0, stream>>>(x, Xb, 8192 * 1024 / 4);
  k_f32_to_bf16<<<dim3(1024), dim3(256), 0, stream>>>(Wout, Woutb, 1024 * 1024 / 4);
  k_prep_weff<<<dim3(12288), dim3(256), 0, stream>>>(Wqkv, Wlora, blora, Aq, Bq, Av, Bv, Weff, beff);
  k_gemm_qkv<<<dim3(24, 64), dim3(256), 0, stream>>>(Xb, Weff, beff, Y, Vt);
  k_attn<<<dim3(16, 64), dim3(256), 0, stream>>>(Y, Vt, Oa);
  k_gemm_out<<<dim3(8, 64), dim3(256), 0, stream>>>(Oa, Woutb, bout, out);
}

// Round 4
// 347.371 us; speedup vs baseline: 1.2499x; 1.0203x over previous
//
#include <hip/hip_runtime.h>
#include <hip/hip_bf16.h>

typedef unsigned short u16;
typedef unsigned int u32;
typedef __attribute__((ext_vector_type(8))) short bf16x8;   // 8 bf16 in 4 VGPRs
typedef __attribute__((ext_vector_type(4))) float f32x4;

#define GLDS16(gptr, lptr)                                                        \
  __builtin_amdgcn_global_load_lds(                                               \
      (__attribute__((address_space(1))) const void*)(gptr),                      \
      (__attribute__((address_space(3))) void*)(lptr), 16, 0, 0)

__device__ __forceinline__ u16 f2bf(float f) {
  union { float f; unsigned u; } v; v.f = f;
  unsigned r = v.u + 0x7fffu + ((v.u >> 16) & 1u);   // RNE, finite inputs only
  return (u16)(r >> 16);
}

// pack two f32 -> one u32 of 2 bf16 (RNE) — compiler emits v_cvt_pk_bf16_f32
__device__ __forceinline__ u32 pack_bf2(float a, float b) {
  union { __hip_bfloat162 h2; u32 u; } v;
  v.h2 = __float22bfloat162_rn(make_float2(a, b));
  return v.u;
}

// ---------------- prep: fp32 -> bf16 cast ----------------
__global__ void k_f32_to_bf16(const float* __restrict__ in, u16* __restrict__ out, int n4) {
  int i = blockIdx.x * 256 + threadIdx.x;
  if (i < n4) {
    float4 f = reinterpret_cast<const float4*>(in)[i];
    ushort4 u;
    u.x = f2bf(f.x); u.y = f2bf(f.y); u.z = f2bf(f.z); u.w = f2bf(f.w);
    reinterpret_cast<ushort4*>(out)[i] = u;
  }
}

// ---------------- prep: effective weight W_eff + b_eff ----------------
__global__ void k_prep_weff(const float* __restrict__ Wqkv, const float* __restrict__ Wlora,
                            const float* __restrict__ blora,
                            const float* __restrict__ Aq, const float* __restrict__ Bq,
                            const float* __restrict__ Av, const float* __restrict__ Bv,
                            u16* __restrict__ Weff, float* __restrict__ beff) {
  int idx = blockIdx.x * 256 + threadIdx.x;  // < 3072*1024
  int o = idx >> 10, c = idx & 1023;
  float w = Wqkv[idx];
  if (o < 1024) {
    float lr = 0.f;
#pragma unroll
    for (int r = 0; r < 8; ++r) lr += Bq[o * 8 + r] * Aq[r * 1024 + c];
    w += Wlora[idx] + 0.125f * lr;
  } else if (o >= 2048) {
    int o2 = o - 2048;
    float lr = 0.f;
#pragma unroll
    for (int r = 0; r < 8; ++r) lr += Bv[o2 * 8 + r] * Av[r * 1024 + c];
    w += Wlora[idx] + 0.125f * lr;
  }
  Weff[idx] = f2bf(w);
  if (c == 0) beff[o] = (o < 1024 || o >= 2048) ? blora[o] : 0.f;
}

// ---------------- GEMM1: Y[8192][3072] = Xb @ Weff^T + beff ----------------
// q slice scaled by log2(e)/8 (softmax scale folded, exp2-domain for k_attn).
__global__ __launch_bounds__(256, 2)
void k_gemm_qkv(const u16* __restrict__ Xb, const u16* __restrict__ Weff,
                const float* __restrict__ beff, u16* __restrict__ Y) {
  __shared__ u16 As[128 * 32], Bs[128 * 32];
  const int tid = threadIdx.x, lane = tid & 63, wave = tid >> 6;
  const int lr = lane & 15, lg = lane >> 4;
  const int wr = wave >> 1, wc = wave & 1;
  const int m0 = blockIdx.y * 128, n0 = blockIdx.x * 128;
  f32x4 acc[4][4] = {};

  for (int k0 = 0; k0 < 1024; k0 += 32) {
#pragma unroll
    for (int i = 0; i < 2; ++i) {
      int gc = ((tid & 3) ^ ((tid >> 2) & 3)) << 3;
      GLDS16(Xb + (size_t)(m0 + i * 64 + (tid >> 2)) * 1024 + k0 + gc, As + i * 2048 + wave * 512);
      GLDS16(Weff + (size_t)(n0 + i * 64 + (tid >> 2)) * 1024 + k0 + gc, Bs + i * 2048 + wave * 512);
    }
    __syncthreads();
    bf16x8 af[4], bfr[4];
#pragma unroll
    for (int t = 0; t < 4; ++t) {
      int ch = ((lg ^ (lr & 3)) & 3) << 3;
      af[t]  = *reinterpret_cast<const bf16x8*>(As + (wr * 64 + t * 16 + lr) * 32 + ch);
      bfr[t] = *reinterpret_cast<const bf16x8*>(Bs + (wc * 64 + t * 16 + lr) * 32 + ch);
    }
#pragma unroll
    for (int mi = 0; mi < 4; ++mi)
#pragma unroll
      for (int ni = 0; ni < 4; ++ni)
        acc[mi][ni] = __builtin_amdgcn_mfma_f32_16x16x32_bf16(af[mi], bfr[ni], acc[mi][ni], 0, 0, 0);
    __syncthreads();
  }

#pragma unroll
  for (int mi = 0; mi < 4; ++mi) {
    int row = m0 + wr * 64 + mi * 16 + (lg << 2);
#pragma unroll
    for (int ni = 0; ni < 4; ++ni) {
      int col = n0 + wc * 64 + ni * 16 + lr;
      float bias = beff[col];
#pragma unroll
      for (int j = 0; j < 4; ++j) {
        float v = acc[mi][ni][j] + bias;
        if (col < 1024) v *= 0.18033688011112042f;  // log2(e)/8: softmax scale + exp2 domain
        Y[(size_t)(row + j) * 3072 + col] = f2bf(v);
      }
    }
  }
}

// ---------------- Vt transpose: Vt[(b*16+h)*64+d][n] = Y[b*2048+n][2048+h*64+d] ----------------
__global__ __launch_bounds__(256)
void k_vtrans(const u16* __restrict__ Y, u16* __restrict__ Vt) {
  __shared__ u16 Ls[64 * 65];
  const int t = threadIdx.x;
  const int bh = blockIdx.y, b = bh >> 4, h = bh & 15;
  const int n0 = blockIdx.x * 64;
#pragma unroll
  for (int c = 0; c < 2; ++c) {
    int idx = c * 256 + t;
    int nl = idx >> 3, d0 = (idx & 7) * 8;
    bf16x8 val = *reinterpret_cast<const bf16x8*>(
        Y + (size_t)(b * 2048 + n0 + nl) * 3072 + 2048 + h * 64 + d0);
#pragma unroll
    for (int j = 0; j < 8; ++j) Ls[(d0 + j) * 65 + nl] = (u16)val[j];
  }
  __syncthreads();
#pragma unroll
  for (int c = 0; c < 2; ++c) {
    int idx = c * 256 + t;
    int dl = idx >> 3, nn = (idx & 7) * 8;
    bf16x8 outv;
#pragma unroll
    for (int j = 0; j < 8; ++j) outv[j] = (short)Ls[dl * 65 + nn + j];
    *reinterpret_cast<bf16x8*>(Vt + (size_t)(bh * 64 + dl) * 2048 + n0 + nn) = outv;
  }
}

// ---------------- flash attention (swapped-QK^T, exp2 softmax, dbuf K/V) ----------------
// Block: one (b,h), 128 Q rows; 4 waves x 32 rows each.  64-key tiles.
// T3-minimum pipeline: stage(kt+1) -> vmcnt(4) -> s_barrier -> compute(kt) -> s_barrier.
__global__ __launch_bounds__(256, 3)
void k_attn(const u16* __restrict__ Y, const u16* __restrict__ Vt, u16* __restrict__ Oa) {
  __shared__ u16 Ks[2][64 * 64], Vs[2][64 * 64];
  __shared__ u32 Pp[4 * 16 * 32];   // per wave: 16 qrows x 32 u32 (64 keys bf16), XOR-swizzled
  const int tid = threadIdx.x, lane = tid & 63, wave = tid >> 6;
  const int b = blockIdx.y >> 4, h = blockIdx.y & 15;
  const int q0 = blockIdx.x * 128;
  const int lr = lane & 15, lg = lane >> 4;
  const size_t bq = (size_t)b * 2048;
  const size_t bv = (size_t)b * 1024 + h * 64;
  const int hc = h * 64;

  // Q fragments (B-operand: n=qrow=lr, k-chunk = hf*32 + lg*8) — Q pre-scaled by log2e/8
  bf16x8 qa[2][2];
#pragma unroll
  for (int g = 0; g < 2; ++g) {
    size_t row = bq + q0 + wave * 32 + g * 16 + lr;
#pragma unroll
    for (int hf = 0; hf < 2; ++hf)
      qa[g][hf] = *reinterpret_cast<const bf16x8*>(Y + row * 3072 + hc + hf * 32 + lg * 8);
  }

  float m_run[2] = {-1e30f, -1e30f}, l_run[2] = {0.f, 0.f};
  f32x4 oacc[2][4] = {};

  const int sr = tid >> 3, sc = tid & 7;
  const u32 pbase = wave * 512 + lr * 32;          // u32 index of this lane's P row
  const u32 pswz  = (lr & 7) << 4;                 // byte-XOR swizzle field

  auto stage = [&](int key0, int bb) {
#pragma unroll
    for (int i = 0; i < 2; ++i) {
      int r = i * 32 + sr;
      int gc = (sc ^ (r & 7)) << 3;
      GLDS16(Y + (bq + key0 + r) * 3072 + 1024 + hc + gc, &Ks[bb][i * 2048 + wave * 512]);
      GLDS16(Vt + (bv + r) * 2048 + key0 + gc,            &Vs[bb][i * 2048 + wave * 512]);
    }
  };

  stage(0, 0);
  for (int kt = 0; kt < 32; ++kt) {
    const int cur = kt & 1;
    if (kt < 31) {
      stage((kt + 1) * 64, cur ^ 1);
      asm volatile("s_waitcnt vmcnt(4)" ::: "memory");   // drain tile kt, keep kt+1 in flight
    } else {
      asm volatile("s_waitcnt vmcnt(0)" ::: "memory");
    }
    __builtin_amdgcn_s_barrier();
    asm volatile("" ::: "memory");

    bf16x8 kb[4][2], vb[4][2];
#pragma unroll
    for (int s = 0; s < 4; ++s) {
      int row = s * 16 + lr;
#pragma unroll
      for (int hf = 0; hf < 2; ++hf) {
        int ch = ((hf * 4 + lg) ^ (row & 7)) << 3;
        kb[s][hf] = *reinterpret_cast<const bf16x8*>(&Ks[cur][row * 64 + ch]);
        vb[s][hf] = *reinterpret_cast<const bf16x8*>(&Vs[cur][row * 64 + ch]);
      }
    }

#pragma unroll
    for (int g = 0; g < 2; ++g) {
      // S^T tiles: C row = key (lg*4+j within s-tile), C col = qrow (lr)
      f32x4 p4[4] = {};
      __builtin_amdgcn_s_setprio(1);
#pragma unroll
      for (int s = 0; s < 4; ++s)
#pragma unroll
        for (int hf = 0; hf < 2; ++hf)
          p4[s] = __builtin_amdgcn_mfma_f32_16x16x32_bf16(kb[s][hf], qa[g][hf], p4[s], 0, 0, 0);
      __builtin_amdgcn_s_setprio(0);

      // row max (base-2 domain): max3-friendly trees, then across the 4 lg-groups
      float ma = fmaxf(fmaxf(p4[0][0], p4[0][1]), fmaxf(p4[0][2], p4[0][3]));
      float mb = fmaxf(fmaxf(p4[1][0], p4[1][1]), fmaxf(p4[1][2], p4[1][3]));
      float mc = fmaxf(fmaxf(p4[2][0], p4[2][1]), fmaxf(p4[2][2], p4[2][3]));
      float md = fmaxf(fmaxf(p4[3][0], p4[3][1]), fmaxf(p4[3][2], p4[3][3]));
      float tmax = fmaxf(fmaxf(ma, mb), fmaxf(mc, md));
      tmax = fmaxf(tmax, __shfl_xor(tmax, 16));
      tmax = fmaxf(tmax, __shfl_xor(tmax, 32));

      // defer-max (T13): 2^11 bound on P — only rescale when max really grew
      if (__any(tmax > m_run[g] + 11.0f)) {
        float mnew = fmaxf(m_run[g], tmax);
        float alpha = __builtin_amdgcn_exp2f(m_run[g] - mnew);
        m_run[g] = mnew;
        l_run[g] *= alpha;
        float abc[4];
#pragma unroll
        for (int j = 0; j < 4; ++j) abc[j] = __shfl(alpha, (lg << 2) + j);
#pragma unroll
        for (int dt = 0; dt < 4; ++dt)
#pragma unroll
          for (int j = 0; j < 4; ++j) oacc[g][dt][j] *= abc[j];
      }

      // P = exp2(S - m), pack to bf16 pairs, row-sum
      float rs = 0.f;
      u32 w[4][2];
#pragma unroll
      for (int s = 0; s < 4; ++s) {
        float e0 = __builtin_amdgcn_exp2f(p4[s][0] - m_run[g]);
        float e1 = __builtin_amdgcn_exp2f(p4[s][1] - m_run[g]);
        float e2 = __builtin_amdgcn_exp2f(p4[s][2] - m_run[g]);
        float e3 = __builtin_amdgcn_exp2f(p4[s][3] - m_run[g]);
        rs += (e0 + e1) + (e2 + e3);
        w[s][0] = pack_bf2(e0, e1);
        w[s][1] = pack_bf2(e2, e3);
      }
      rs += __shfl_xor(rs, 16);
      rs += __shfl_xor(rs, 32);
      l_run[g] += rs;

      // scatter P^T into per-wave LDS: key K lives at u32 index K/2 of row lr
#pragma unroll
      for (int s = 0; s < 4; ++s) {
        u32 ui = pbase + ((((u32)(s * 32 + lg * 8)) ^ pswz) >> 2);
        *reinterpret_cast<uint2*>(&Pp[ui]) = make_uint2(w[s][0], w[s][1]);
      }
      asm volatile("s_waitcnt lgkmcnt(0)" ::: "memory");
      __builtin_amdgcn_sched_barrier(0);

      // PV: A-frag chunk kk = keys kk*32 + lg*8 .. +7  (matches vb's k-slot convention)
      __builtin_amdgcn_s_setprio(1);
#pragma unroll
      for (int kk = 0; kk < 2; ++kk) {
        u32 ur = pbase + ((((u32)(kk * 64 + lg * 16)) ^ pswz) >> 2);
        bf16x8 pa = *reinterpret_cast<const bf16x8*>(&Pp[ur]);
#pragma unroll
        for (int dt = 0; dt < 4; ++dt)
          oacc[g][dt] = __builtin_amdgcn_mfma_f32_16x16x32_bf16(pa, vb[dt][kk], oacc[g][dt], 0, 0, 0);
      }
      __builtin_amdgcn_s_setprio(0);
    }
    asm volatile("" ::: "memory");
    __builtin_amdgcn_s_barrier();
  }

#pragma unroll
  for (int g = 0; g < 2; ++g) {
    float lbc[4];
#pragma unroll
    for (int j = 0; j < 4; ++j)
      lbc[j] = __builtin_amdgcn_rcpf(__shfl(l_run[g], (lg << 2) + j));
    int rowb = (int)bq + q0 + wave * 32 + g * 16 + (lg << 2);
#pragma unroll
    for (int dt = 0; dt < 4; ++dt) {
      int col = hc + dt * 16 + lr;
#pragma unroll
      for (int j = 0; j < 4; ++j) {
        float v = oacc[g][dt][j] * lbc[j];
        Oa[(size_t)(rowb + j) * 1024 + col] = f2bf(v);
      }
    }
  }
}

// ---------------- GEMM2: out[8192][1024] = Oa @ Wout^T + b_out (fp32) ----------------
__global__ __launch_bounds__(256, 2)
void k_gemm_out(const u16* __restrict__ Ob, const u16* __restrict__ Wb,
                const float* __restrict__ bout, float* __restrict__ out) {
  __shared__ u16 As[128 * 32], Bs[128 * 32];
  const int tid = threadIdx.x, lane = tid & 63, wave = tid >> 6;
  const int lr = lane & 15, lg = lane >> 4;
  const int wr = wave >> 1, wc = wave & 1;
  const int m0 = blockIdx.y * 128, n0 = blockIdx.x * 128;
  f32x4 acc[4][4] = {};

  for (int k0 = 0; k0 < 1024; k0 += 32) {
#pragma unroll
    for (int i = 0; i < 2; ++i) {
      int gc = ((tid & 3) ^ ((tid >> 2) & 3)) << 3;
      GLDS16(Ob + (size_t)(m0 + i * 64 + (tid >> 2)) * 1024 + k0 + gc, As + i * 2048 + wave * 512);
      GLDS16(Wb + (size_t)(n0 + i * 64 + (tid >> 2)) * 1024 + k0 + gc, Bs + i * 2048 + wave * 512);
    }
    __syncthreads();
    bf16x8 af[4], bfr[4];
#pragma unroll
    for (int t = 0; t < 4; ++t) {
      int ch = ((lg ^ (lr & 3)) & 3) << 3;
      af[t]  = *reinterpret_cast<const bf16x8*>(As + (wr * 64 + t * 16 + lr) * 32 + ch);
      bfr[t] = *reinterpret_cast<const bf16x8*>(Bs + (wc * 64 + t * 16 + lr) * 32 + ch);
    }
#pragma unroll
    for (int mi = 0; mi < 4; ++mi)
#pragma unroll
      for (int ni = 0; ni < 4; ++ni)
        acc[mi][ni] = __builtin_amdgcn_mfma_f32_16x16x32_bf16(af[mi], bfr[ni], acc[mi][ni], 0, 0, 0);
    __syncthreads();
  }

#pragma unroll
  for (int mi = 0; mi < 4; ++mi) {
    int row = m0 + wr * 64 + mi * 16 + (lg << 2);
#pragma unroll
    for (int ni = 0; ni < 4; ++ni) {
      int col = n0 + wc * 64 + ni * 16 + lr;
      float bias = bout[col];
#pragma unroll
      for (int j = 0; j < 4; ++j)
        out[(size_t)(row + j) * 1024 + col] = acc[mi][ni][j] + bias;
    }
  }
}

extern "C" void kernel_launch(void* const* d_in, const int* in_sizes, int n_in,
                              void* d_out, int out_size, void* d_ws, size_t ws_size,
                              hipStream_t stream) {
  const float* x     = (const float*)d_in[0];
  const float* Wqkv  = (const float*)d_in[1];
  const float* Wlora = (const float*)d_in[2];
  const float* blora = (const float*)d_in[3];
  const float* Aq    = (const float*)d_in[4];
  const float* Bq    = (const float*)d_in[5];
  const float* Av    = (const float*)d_in[6];
  const float* Bv    = (const float*)d_in[7];
  const float* Wout  = (const float*)d_in[8];
  const float* bout  = (const float*)d_in[9];
  float* out = (float*)d_out;

  char* w = (char*)d_ws;
  auto alloc = [&](size_t bytes) { char* p = w; w += (bytes + 255) & ~(size_t)255; return p; };
  u16*   Xb    = (u16*)alloc((size_t)8192 * 1024 * 2);   // x bf16  (reused as Oa later)
  u16*   Weff  = (u16*)alloc((size_t)3072 * 1024 * 2);
  float* beff  = (float*)alloc((size_t)3072 * 4);
  u16*   Woutb = (u16*)alloc((size_t)1024 * 1024 * 2);
  u16*   Y     = (u16*)alloc((size_t)8192 * 3072 * 2);   // qkv (q pre-scaled by log2e/8)
  u16*   Vt    = (u16*)alloc((size_t)4096 * 1024 * 2 * 2); // [(b*16+h)*64+d][2048] bf16
  u16*   Oa    = Xb;  // alias: Xb is dead after GEMM1

  k_f32_to_bf16<<<dim3(8192), dim3(256), 0, stream>>>(x, Xb, 8192 * 1024 / 4);
  k_f32_to_bf16<<<dim3(1024), dim3(256), 0, stream>>>(Wout, Woutb, 1024 * 1024 / 4);
  k_prep_weff<<<dim3(12288), dim3(256), 0, stream>>>(Wqkv, Wlora, blora, Aq, Bq, Av, Bv, Weff, beff);
  k_gemm_qkv<<<dim3(24, 64), dim3(256), 0, stream>>>(Xb, Weff, beff, Y);
  k_vtrans<<<dim3(32, 64), dim3(256), 0, stream>>>(Y, Vt);
  k_attn<<<dim3(16, 64), dim3(256), 0, stream>>>(Y, Vt, Oa);
  k_gemm_out<<<dim3(8, 64), dim3(256), 0, stream>>>(Oa, Woutb, bout, out);
}

// Round 6
// 335.456 us; speedup vs baseline: 1.2943x; 1.0355x over previous
//
#include <hip/hip_runtime.h>
#include <hip/hip_bf16.h>

typedef unsigned short u16;
typedef unsigned int u32;
typedef __attribute__((ext_vector_type(8))) short bf16x8;   // 8 bf16 in 4 VGPRs
typedef __attribute__((ext_vector_type(4))) float f32x4;
typedef __attribute__((ext_vector_type(16))) float f32x16;

#define GLDS16(gptr, lptr)                                                        \
  __builtin_amdgcn_global_load_lds(                                               \
      (__attribute__((address_space(1))) const void*)(gptr),                      \
      (__attribute__((address_space(3))) void*)(lptr), 16, 0, 0)

__device__ __forceinline__ u16 f2bf(float f) {
  union { float f; unsigned u; } v; v.f = f;
  unsigned r = v.u + 0x7fffu + ((v.u >> 16) & 1u);   // RNE, finite inputs only
  return (u16)(r >> 16);
}

// pack two f32 -> one u32 of 2 bf16 (RNE) — compiler emits v_cvt_pk_bf16_f32
__device__ __forceinline__ u32 pack_bf2(float a, float b) {
  union { __hip_bfloat162 h2; u32 u; } v;
  v.h2 = __float22bfloat162_rn(make_float2(a, b));
  return v.u;
}

// ---------------- prep: fp32 -> bf16 cast ----------------
__global__ void k_f32_to_bf16(const float* __restrict__ in, u16* __restrict__ out, int n4) {
  int i = blockIdx.x * 256 + threadIdx.x;
  if (i < n4) {
    float4 f = reinterpret_cast<const float4*>(in)[i];
    ushort4 u;
    u.x = f2bf(f.x); u.y = f2bf(f.y); u.z = f2bf(f.z); u.w = f2bf(f.w);
    reinterpret_cast<ushort4*>(out)[i] = u;
  }
}

// ---------------- prep: effective weight W_eff + b_eff ----------------
__global__ void k_prep_weff(const float* __restrict__ Wqkv, const float* __restrict__ Wlora,
                            const float* __restrict__ blora,
                            const float* __restrict__ Aq, const float* __restrict__ Bq,
                            const float* __restrict__ Av, const float* __restrict__ Bv,
                            u16* __restrict__ Weff, float* __restrict__ beff) {
  int idx = blockIdx.x * 256 + threadIdx.x;  // < 3072*1024
  int o = idx >> 10, c = idx & 1023;
  float w = Wqkv[idx];
  if (o < 1024) {
    float lr = 0.f;
#pragma unroll
    for (int r = 0; r < 8; ++r) lr += Bq[o * 8 + r] * Aq[r * 1024 + c];
    w += Wlora[idx] + 0.125f * lr;
  } else if (o >= 2048) {
    int o2 = o - 2048;
    float lr = 0.f;
#pragma unroll
    for (int r = 0; r < 8; ++r) lr += Bv[o2 * 8 + r] * Av[r * 1024 + c];
    w += Wlora[idx] + 0.125f * lr;
  }
  Weff[idx] = f2bf(w);
  if (c == 0) beff[o] = (o < 1024 || o >= 2048) ? blora[o] : 0.f;
}

// ---------------- GEMM1: Y[8192][3072] = Xb @ Weff^T + beff ----------------
// q slice scaled by log2(e)/8 (softmax scale folded, exp2-domain for k_attn).
__global__ __launch_bounds__(256, 2)
void k_gemm_qkv(const u16* __restrict__ Xb, const u16* __restrict__ Weff,
                const float* __restrict__ beff, u16* __restrict__ Y) {
  __shared__ u16 As[128 * 32], Bs[128 * 32];
  const int tid = threadIdx.x, lane = tid & 63, wave = tid >> 6;
  const int lr = lane & 15, lg = lane >> 4;
  const int wr = wave >> 1, wc = wave & 1;
  const int m0 = blockIdx.y * 128, n0 = blockIdx.x * 128;
  f32x4 acc[4][4] = {};

  for (int k0 = 0; k0 < 1024; k0 += 32) {
#pragma unroll
    for (int i = 0; i < 2; ++i) {
      int gc = ((tid & 3) ^ ((tid >> 2) & 3)) << 3;
      GLDS16(Xb + (size_t)(m0 + i * 64 + (tid >> 2)) * 1024 + k0 + gc, As + i * 2048 + wave * 512);
      GLDS16(Weff + (size_t)(n0 + i * 64 + (tid >> 2)) * 1024 + k0 + gc, Bs + i * 2048 + wave * 512);
    }
    __syncthreads();
    bf16x8 af[4], bfr[4];
#pragma unroll
    for (int t = 0; t < 4; ++t) {
      int ch = ((lg ^ (lr & 3)) & 3) << 3;
      af[t]  = *reinterpret_cast<const bf16x8*>(As + (wr * 64 + t * 16 + lr) * 32 + ch);
      bfr[t] = *reinterpret_cast<const bf16x8*>(Bs + (wc * 64 + t * 16 + lr) * 32 + ch);
    }
#pragma unroll
    for (int mi = 0; mi < 4; ++mi)
#pragma unroll
      for (int ni = 0; ni < 4; ++ni)
        acc[mi][ni] = __builtin_amdgcn_mfma_f32_16x16x32_bf16(af[mi], bfr[ni], acc[mi][ni], 0, 0, 0);
    __syncthreads();
  }

#pragma unroll
  for (int mi = 0; mi < 4; ++mi) {
    int row = m0 + wr * 64 + mi * 16 + (lg << 2);
#pragma unroll
    for (int ni = 0; ni < 4; ++ni) {
      int col = n0 + wc * 64 + ni * 16 + lr;
      float bias = beff[col];
#pragma unroll
      for (int j = 0; j < 4; ++j) {
        float v = acc[mi][ni][j] + bias;
        if (col < 1024) v *= 0.18033688011112042f;  // log2(e)/8: softmax scale + exp2 domain
        Y[(size_t)(row + j) * 3072 + col] = f2bf(v);
      }
    }
  }
}

// ---------------- Vt transpose: Vt[(b*16+h)*64+d][n] = Y[b*2048+n][2048+h*64+d] ----------------
__global__ __launch_bounds__(256)
void k_vtrans(const u16* __restrict__ Y, u16* __restrict__ Vt) {
  __shared__ u16 Ls[64 * 65];
  const int t = threadIdx.x;
  const int bh = blockIdx.y, b = bh >> 4, h = bh & 15;
  const int n0 = blockIdx.x * 64;
#pragma unroll
  for (int c = 0; c < 2; ++c) {
    int idx = c * 256 + t;
    int nl = idx >> 3, d0 = (idx & 7) * 8;
    bf16x8 val = *reinterpret_cast<const bf16x8*>(
        Y + (size_t)(b * 2048 + n0 + nl) * 3072 + 2048 + h * 64 + d0);
#pragma unroll
    for (int j = 0; j < 8; ++j) Ls[(d0 + j) * 65 + nl] = (u16)val[j];
  }
  __syncthreads();
#pragma unroll
  for (int c = 0; c < 2; ++c) {
    int idx = c * 256 + t;
    int dl = idx >> 3, nn = (idx & 7) * 8;
    bf16x8 outv;
#pragma unroll
    for (int j = 0; j < 8; ++j) outv[j] = (short)Ls[dl * 65 + nn + j];
    *reinterpret_cast<bf16x8*>(Vt + (size_t)(bh * 64 + dl) * 2048 + n0 + nn) = outv;
  }
}

// ---------------- flash attention: 32x32 swapped QK^T, P fully in-register ----------------
// Block: one (b,h), 128 Q rows; 4 waves x 32 rows each.  64-key tiles, dbuf staging.
// mfma_32x32x16(K,Q): lane owns qrow=lane&31 (32 scores in regs); softmax in-lane.
// P -> bf16 via cvt_pk; permlane32_swap redistributes into exact PV A-fragments.
__global__ __launch_bounds__(256, 3)
void k_attn(const u16* __restrict__ Y, const u16* __restrict__ Vt, u16* __restrict__ Oa) {
  __shared__ u16 Ks[2][64 * 64], Vs[2][64 * 64];
  const int tid = threadIdx.x, lane = tid & 63, wave = tid >> 6;
  const int b = blockIdx.y >> 4, h = blockIdx.y & 15;
  const int q0 = blockIdx.x * 128;
  const int l31 = lane & 31, hi = lane >> 5;
  const size_t bq = (size_t)b * 2048;
  const size_t bv = (size_t)b * 1024 + h * 64;
  const int hc = h * 64;

  // Q B-frags: n=qrow=wave*32+l31, k = d = ks*16 + 8*hi + j  (Q pre-scaled log2e/8)
  bf16x8 qb[4];
  {
    const u16* yr = Y + (bq + q0 + wave * 32 + l31) * 3072 + hc + hi * 8;
#pragma unroll
    for (int ks = 0; ks < 4; ++ks)
      qb[ks] = *reinterpret_cast<const bf16x8*>(yr + ks * 16);
  }

  float m_run = -1e30f, l_run = 0.f;
  f32x16 oacc[2] = {};

  const int sr = tid >> 3, sc = tid & 7;
  auto stage = [&](int key0, int bb) {
#pragma unroll
    for (int i = 0; i < 2; ++i) {
      int r = i * 32 + sr;
      int gc = (sc ^ (r & 7)) << 3;
      GLDS16(Y + (bq + key0 + r) * 3072 + 1024 + hc + gc, &Ks[bb][i * 2048 + wave * 512]);
      GLDS16(Vt + (bv + r) * 2048 + key0 + gc,            &Vs[bb][i * 2048 + wave * 512]);
    }
  };

  stage(0, 0);
  for (int kt = 0; kt < 32; ++kt) {
    const int cur = kt & 1;
    if (kt < 31) {
      stage((kt + 1) * 64, cur ^ 1);
      asm volatile("s_waitcnt vmcnt(4)" ::: "memory");   // drain tile kt, keep kt+1 in flight
    } else {
      asm volatile("s_waitcnt vmcnt(0)" ::: "memory");
    }
    __builtin_amdgcn_s_barrier();
    asm volatile("" ::: "memory");

    // K A-frags: kb[t][ks] = K[key=t*32+l31][d = ks*16+8hi+j]; V B-frags from Vt-tile rows d
    bf16x8 kb[2][4], vb[2][4];
#pragma unroll
    for (int t = 0; t < 2; ++t) {
      const u16* kbase = &Ks[cur][(t * 32 + l31) * 64];
      int rx = (t * 32 + l31) & 7;
#pragma unroll
      for (int ks = 0; ks < 4; ++ks)
        kb[t][ks] = *reinterpret_cast<const bf16x8*>(kbase + (((ks * 2 + hi) ^ rx) << 3));
    }
#pragma unroll
    for (int dt = 0; dt < 2; ++dt) {
      const u16* vbase = &Vs[cur][(dt * 32 + l31) * 64];
      int rx = (dt * 32 + l31) & 7;
#pragma unroll
      for (int ks = 0; ks < 4; ++ks)
        vb[dt][ks] = *reinterpret_cast<const bf16x8*>(vbase + (((ks * 2 + hi) ^ rx) << 3));
    }

    // S^T = K·Q^T: col = qrow (lane-owned), rows = keys in regs
    f32x16 p4[2] = {};
    __builtin_amdgcn_s_setprio(1);
#pragma unroll
    for (int t = 0; t < 2; ++t)
#pragma unroll
      for (int ks = 0; ks < 4; ++ks)
        p4[t] = __builtin_amdgcn_mfma_f32_32x32x16_bf16(kb[t][ks], qb[ks], p4[t], 0, 0, 0);
    __builtin_amdgcn_s_setprio(0);

    // in-lane max over 32 scores (log-depth tree) + one cross-half combine
    float mx[8];
#pragma unroll
    for (int r = 0; r < 8; ++r)
      mx[r] = fmaxf(fmaxf(p4[0][r], p4[0][r + 8]), fmaxf(p4[1][r], p4[1][r + 8]));
#pragma unroll
    for (int s = 4; s > 0; s >>= 1)
#pragma unroll
      for (int r = 0; r < s; ++r) mx[r] = fmaxf(mx[r], mx[r + s]);
    float tmax = fmaxf(mx[0], __shfl_xor(mx[0], 32));

    // defer-max (T13, base-2, THR=11)
    if (__any(tmax > m_run + 11.0f)) {
      float mnew = fmaxf(m_run, tmax);
      float alpha = __builtin_amdgcn_exp2f(m_run - mnew);
      m_run = mnew;
      l_run *= alpha;
#pragma unroll
      for (int r = 0; r < 16; ++r) {
        float ab = __shfl(alpha, (r & 3) + 8 * (r >> 2) + 4 * hi);
        oacc[0][r] *= ab;
        oacc[1][r] *= ab;
      }
    }

    // P = exp2(S - m); pack to bf16 pairs; row-sum (keys reg r=4g+i <-> key 8g+4hi+i)
    float rs = 0.f;
    u32 w[2][4][2];
#pragma unroll
    for (int t = 0; t < 2; ++t)
#pragma unroll
      for (int g = 0; g < 4; ++g) {
        float e0 = __builtin_amdgcn_exp2f(p4[t][4 * g + 0] - m_run);
        float e1 = __builtin_amdgcn_exp2f(p4[t][4 * g + 1] - m_run);
        float e2 = __builtin_amdgcn_exp2f(p4[t][4 * g + 2] - m_run);
        float e3 = __builtin_amdgcn_exp2f(p4[t][4 * g + 3] - m_run);
        rs += (e0 + e1) + (e2 + e3);
        w[t][g][0] = pack_bf2(e0, e1);
        w[t][g][1] = pack_bf2(e2, e3);
      }
    rs += __shfl_xor(rs, 32);
    l_run += rs;

    // redistribute packed P into PV A-frags: pa[ks] = P[qrow=l31][key = ks*16+8hi+j]
    // swap(w[t][2q][i], w[t][2q+1][i]): r[0] -> word i (h=0 block), r[1] -> word i+2 (h=1 block)
    bf16x8 pa[4];
#pragma unroll
    for (int ks = 0; ks < 4; ++ks) {
      const int t = ks >> 1, q2 = (ks & 1) * 2;
      auto s0 = __builtin_amdgcn_permlane32_swap(w[t][q2][0], w[t][q2 + 1][0], false, false);
      auto s1 = __builtin_amdgcn_permlane32_swap(w[t][q2][1], w[t][q2 + 1][1], false, false);
      union { u32 u[4]; bf16x8 v; } cv;
      cv.u[0] = s0[0]; cv.u[1] = s1[0]; cv.u[2] = s0[1]; cv.u[3] = s1[1];
      pa[ks] = cv.v;
    }

    // PV: O[qrow][d] += P·V  (A k = B k = key = ks*16+8hi+j)
    __builtin_amdgcn_s_setprio(1);
#pragma unroll
    for (int ks = 0; ks < 4; ++ks) {
      oacc[0] = __builtin_amdgcn_mfma_f32_32x32x16_bf16(pa[ks], vb[0][ks], oacc[0], 0, 0, 0);
      oacc[1] = __builtin_amdgcn_mfma_f32_32x32x16_bf16(pa[ks], vb[1][ks], oacc[1], 0, 0, 0);
    }
    __builtin_amdgcn_s_setprio(0);

    asm volatile("" ::: "memory");
    __builtin_amdgcn_s_barrier();
  }

  // epilogue: O rows = qrow(reg), cols = dt*32 + l31
  float linv = __builtin_amdgcn_rcpf(l_run);
  const size_t orow0 = bq + q0 + wave * 32;
#pragma unroll
  for (int r = 0; r < 16; ++r) {
    int qr = (r & 3) + 8 * (r >> 2) + 4 * hi;
    float li = __shfl(linv, qr);
    size_t rb = (orow0 + qr) * 1024 + hc + l31;
    Oa[rb]      = f2bf(oacc[0][r] * li);
    Oa[rb + 32] = f2bf(oacc[1][r] * li);
  }
}

// ---------------- GEMM2: out[8192][1024] = Oa @ Wout^T + b_out (fp32) ----------------
__global__ __launch_bounds__(256, 2)
void k_gemm_out(const u16* __restrict__ Ob, const u16* __restrict__ Wb,
                const float* __restrict__ bout, float* __restrict__ out) {
  __shared__ u16 As[128 * 32], Bs[128 * 32];
  const int tid = threadIdx.x, lane = tid & 63, wave = tid >> 6;
  const int lr = lane & 15, lg = lane >> 4;
  const int wr = wave >> 1, wc = wave & 1;
  const int m0 = blockIdx.y * 128, n0 = blockIdx.x * 128;
  f32x4 acc[4][4] = {};

  for (int k0 = 0; k0 < 1024; k0 += 32) {
#pragma unroll
    for (int i = 0; i < 2; ++i) {
      int gc = ((tid & 3) ^ ((tid >> 2) & 3)) << 3;
      GLDS16(Ob + (size_t)(m0 + i * 64 + (tid >> 2)) * 1024 + k0 + gc, As + i * 2048 + wave * 512);
      GLDS16(Wb + (size_t)(n0 + i * 64 + (tid >> 2)) * 1024 + k0 + gc, Bs + i * 2048 + wave * 512);
    }
    __syncthreads();
    bf16x8 af[4], bfr[4];
#pragma unroll
    for (int t = 0; t < 4; ++t) {
      int ch = ((lg ^ (lr & 3)) & 3) << 3;
      af[t]  = *reinterpret_cast<const bf16x8*>(As + (wr * 64 + t * 16 + lr) * 32 + ch);
      bfr[t] = *reinterpret_cast<const bf16x8*>(Bs + (wc * 64 + t * 16 + lr) * 32 + ch);
    }
#pragma unroll
    for (int mi = 0; mi < 4; ++mi)
#pragma unroll
      for (int ni = 0; ni < 4; ++ni)
        acc[mi][ni] = __builtin_amdgcn_mfma_f32_16x16x32_bf16(af[mi], bfr[ni], acc[mi][ni], 0, 0, 0);
    __syncthreads();
  }

#pragma unroll
  for (int mi = 0; mi < 4; ++mi) {
    int row = m0 + wr * 64 + mi * 16 + (lg << 2);
#pragma unroll
    for (int ni = 0; ni < 4; ++ni) {
      int col = n0 + wc * 64 + ni * 16 + lr;
      float bias = bout[col];
#pragma unroll
      for (int j = 0; j < 4; ++j)
        out[(size_t)(row + j) * 1024 + col] = acc[mi][ni][j] + bias;
    }
  }
}

extern "C" void kernel_launch(void* const* d_in, const int* in_sizes, int n_in,
                              void* d_out, int out_size, void* d_ws, size_t ws_size,
                              hipStream_t stream) {
  const float* x     = (const float*)d_in[0];
  const float* Wqkv  = (const float*)d_in[1];
  const float* Wlora = (const float*)d_in[2];
  const float* blora = (const float*)d_in[3];
  const float* Aq    = (const float*)d_in[4];
  const float* Bq    = (const float*)d_in[5];
  const float* Av    = (const float*)d_in[6];
  const float* Bv    = (const float*)d_in[7];
  const float* Wout  = (const float*)d_in[8];
  const float* bout  = (const float*)d_in[9];
  float* out = (float*)d_out;

  char* w = (char*)d_ws;
  auto alloc = [&](size_t bytes) { char* p = w; w += (bytes + 255) & ~(size_t)255; return p; };
  u16*   Xb    = (u16*)alloc((size_t)8192 * 1024 * 2);   // x bf16  (reused as Oa later)
  u16*   Weff  = (u16*)alloc((size_t)3072 * 1024 * 2);
  float* beff  = (float*)alloc((size_t)3072 * 4);
  u16*   Woutb = (u16*)alloc((size_t)1024 * 1024 * 2);
  u16*   Y     = (u16*)alloc((size_t)8192 * 3072 * 2);   // qkv (q pre-scaled by log2e/8)
  u16*   Vt    = (u16*)alloc((size_t)4096 * 1024 * 2 * 2); // [(b*16+h)*64+d][2048] bf16
  u16*   Oa    = Xb;  // alias: Xb is dead after GEMM1

  k_f32_to_bf16<<<dim3(8192), dim3(256), 0, stream>>>(x, Xb, 8192 * 1024 / 4);
  k_f32_to_bf16<<<dim3(1024), dim3(256), 0, stream>>>(Wout, Woutb, 1024 * 1024 / 4);
  k_prep_weff<<<dim3(12288), dim3(256), 0, stream>>>(Wqkv, Wlora, blora, Aq, Bq, Av, Bv, Weff, beff);
  k_gemm_qkv<<<dim3(24, 64), dim3(256), 0, stream>>>(Xb, Weff, beff, Y);
  k_vtrans<<<dim3(32, 64), dim3(256), 0, stream>>>(Y, Vt);
  k_attn<<<dim3(16, 64), dim3(256), 0, stream>>>(Y, Vt, Oa);
  k_gemm_out<<<dim3(8, 64), dim3(256), 0, stream>>>(Oa, Woutb, bout, out);
}